// Round 7
// baseline (129.334 us; speedup 1.0000x reference)
//
#include <hip/hip_runtime.h>
#include <hip/hip_bf16.h>

// RestrictedNN DAG. Round 11: fuse root into k_tree WITHOUT fences.
//  - R7's lesson: __threadfence = buffer_wbl2 (full L2 writeback) per block
//    -> 2.1 GB writes. Instead: h2 handoff uses __hip_atomic_store/load
//    (RELAXED, AGENT scope) = sc-flagged cache-bypass ops straight to the
//    shared MALL; __syncthreads' vmcnt drain orders them before the per-tile
//    relaxed agent fetch_add. 8th block of a tile computes the root in-block.
//  - k_root kernel deleted. Everything else identical to round 10b
//    (phase A on matrix pipe via folded Wg*W0 fragment table, cvt_pk bf16
//    packing, XOR-swizzled xs/h0s).
// B=4096, L0=512 leaves (G=8,H=16), L1=64, L2=8 (FAN=8), root 128->16.

#define TB 16
#define H1S 136      // ushorts per h1 row (128+8): rows 16B-aligned

typedef __attribute__((ext_vector_type(8))) short short8;
typedef __attribute__((ext_vector_type(4))) float floatx4;

__device__ __forceinline__ float sigf(float v) {
    return __builtin_amdgcn_rcpf(1.0f + __expf(-v));
}
// packed f32x2 -> bf16x2 (RNE). Compiler emits v_cvt_pk_bf16_f32.
__device__ __forceinline__ unsigned int f2bf2(float lo, float hi) {
    __hip_bfloat162 p = __float22bfloat162_rn(make_float2(lo, hi));
    unsigned int u;
    __builtin_memcpy(&u, &p, 4);
    return u;
}
__device__ __forceinline__ unsigned short f2bf(float f) {
    __hip_bfloat16 b = __float2bfloat16(f);
    unsigned short u;
    __builtin_memcpy(&u, &b, 2);
    return u;
}

// ---- prep ----
// blocks 0..71 : transpose W1/W2 per module to bf16 [h][k] fragment layout
// blocks 72..135: build W0f (per-module 64-lane A-frag table, bf16 Wg*W0,
//                zero K-pad) and bias0 (f32, = bg . W0)
// block 0 also zeroes the per-tile completion counters.
__global__ __launch_bounds__(256) void k_prep(
    const float* __restrict__ W1, const float* __restrict__ W2,
    const float* __restrict__ Wg, const float* __restrict__ bg,
    const float* __restrict__ W0,
    unsigned short* __restrict__ W1t, unsigned short* __restrict__ W2t,
    unsigned short* __restrict__ W0f, float* __restrict__ bias0g,
    int* __restrict__ cnt)
{
    __shared__ float wl[128 * 17];
    const int mb  = blockIdx.x;
    const int tid = threadIdx.x;
    if (mb == 0) cnt[tid] = 0;              // 256 tiles; kernel-end release
    if (mb < 72) {
        const float* src = (mb < 64) ? (W1 + (size_t)mb * 2048)
                                     : (W2 + (size_t)(mb - 64) * 2048);
        unsigned short* dst = (mb < 64) ? (W1t + (size_t)mb * 2048)
                                        : (W2t + (size_t)(mb - 64) * 2048);
#pragma unroll
        for (int i = 0; i < 8; ++i) {
            const int idx = tid + i * 256;      // [k][h] in, coalesced
            wl[(idx >> 4) * 17 + (idx & 15)] = src[idx];
        }
        __syncthreads();
#pragma unroll
        for (int i = 0; i < 4; ++i) {
            const int u  = tid + i * 256;       // uint index over [h][k] bf16 out
            const int h  = u >> 6;
            const int k  = (u & 63) * 2;
            ((unsigned int*)dst)[u] = f2bf2(wl[k * 17 + h], wl[(k + 1) * 17 + h]);
        }
    } else {
        const int idx = mb - 72;                // 0..63, 8 modules each
        const int sub = tid >> 6, l = tid & 63;
#pragma unroll
        for (int it = 0; it < 2; ++it) {
            const int m = idx * 8 + it * 4 + sub;
            uint4 v = make_uint4(0u, 0u, 0u, 0u);
            if (l < 16) {
                float p[8];
                float bsum = 0.f;
#pragma unroll
                for (int j = 0; j < 8; ++j) {
                    const float w = W0[(size_t)m * 128 + j * 16 + l];
                    p[j] = Wg[m * 8 + j] * w;
                    bsum = fmaf(bg[m * 8 + j], w, bsum);
                }
                v.x = f2bf2(p[0], p[1]);
                v.y = f2bf2(p[2], p[3]);
                v.z = f2bf2(p[4], p[5]);
                v.w = f2bf2(p[6], p[7]);
                bias0g[m * 16 + l] = bsum;
            }
            *(uint4*)(W0f + (size_t)m * 512 + l * 8) = v;
        }
    }
}

// 2x4-deep software-pipeline regs for phase A (static indices only)
struct FragG { uint4 a0, a1, a2, a3; float4 b0, b1, b2, b3; };

__device__ __forceinline__ void load4(FragG& f, const unsigned short* w0fp,
                                      const float* bp, int g) {
    f.a0 = *(const uint4*)(w0fp + (size_t)(g * 4 + 0) * 512);
    f.a1 = *(const uint4*)(w0fp + (size_t)(g * 4 + 1) * 512);
    f.a2 = *(const uint4*)(w0fp + (size_t)(g * 4 + 2) * 512);
    f.a3 = *(const uint4*)(w0fp + (size_t)(g * 4 + 3) * 512);
    f.b0 = *(const float4*)(bp + (g * 4 + 0) * 16);
    f.b1 = *(const float4*)(bp + (g * 4 + 1) * 16);
    f.b2 = *(const float4*)(bp + (g * 4 + 2) * 16);
    f.b3 = *(const float4*)(bp + (g * 4 + 3) * 16);
}

__device__ __forceinline__ void comp4(const FragG& f, int g, int m0,
                                      const char* xrd, char* h0wr,
                                      int brow, int q) {
#pragma unroll
    for (int i = 0; i < 4; ++i) {
        const uint4  a4 = (i == 0) ? f.a0 : (i == 1) ? f.a1 : (i == 2) ? f.a2 : f.a3;
        const float4 b4 = (i == 0) ? f.b0 : (i == 1) ? f.b1 : (i == 2) ? f.b2 : f.b3;
        const int mloc = m0 + g * 4 + i;
        const short8 bv = *(const short8*)(xrd + ((mloc * 16) ^ ((brow & 7) << 4)));
        floatx4 acc = {b4.x, b4.y, b4.z, b4.w};
        acc = __builtin_amdgcn_mfma_f32_16x16x32_bf16(
                  __builtin_bit_cast(short8, a4), bv, acc, 0, 0, 0);
        *(uint2*)(h0wr + ((mloc * 32 + q * 8) ^ ((brow & 7) << 4))) =
            make_uint2(f2bf2(sigf(acc[0]), sigf(acc[1])),
                       f2bf2(sigf(acc[2]), sigf(acc[3])));
    }
}

__global__ __launch_bounds__(256, 3) void k_tree(
    const float* __restrict__ x,
    const unsigned short* __restrict__ W0f, const float* __restrict__ bias0g,
    const unsigned short* __restrict__ W1t, const unsigned short* __restrict__ W2t,
    const float* __restrict__ W3, const float* __restrict__ Wf,
    float* __restrict__ h2ws, int* __restrict__ cnt, float* __restrict__ out)
{
    __shared__ __align__(16) unsigned short xs[16 * 512];     // 16384 B (h1/root reuse)
    __shared__ __align__(16) unsigned short h0s[16 * 1024];   // 32768 B, swizzled
    __shared__ int lastflag;
    unsigned short* h1u = xs;   // h1 [b][j*16+h] bf16, stride H1S; xs dead after A

    const int tid  = threadIdx.x;
    const int s    = blockIdx.x & 7;
    const int tile = blockIdx.x >> 3;
    const int b0   = tile * TB;
    const int lane = tid & 63;
    const int wv   = tid >> 6;
    const int n    = lane & 15, q = lane >> 4;

    // ---------- issue x stage loads (oldest in pipe), convert as they land ----
    const float* xbase = x + (size_t)b0 * 4096 + s * 512;
    uint2 xp[8];
#pragma unroll
    for (int t = 0; t < 8; ++t) {
        const int i = tid + t * 256;           // over TB*128 float4s
        const int r = i >> 7, c4 = i & 127;
        const float4 v = *(const float4*)(xbase + (size_t)r * 4096 + c4 * 4);
        xp[t] = make_uint2(f2bf2(v.x, v.y), f2bf2(v.z, v.w));
    }

    // ---------- prefetch phase-B/C MFMA B-fragments ----------
    short8 w1r[2][4];
#pragma unroll
    for (int jj = 0; jj < 2; ++jj) {
        const unsigned short* w1m =
            W1t + ((size_t)(s * 8 + wv * 2 + jj) * 16 + n) * 128 + q * 8;
#pragma unroll
        for (int ks = 0; ks < 4; ++ks)
            w1r[jj][ks] = *(const short8*)(w1m + ks * 32);
    }
    short8 w2r[4];
    if (wv == 0) {
        const unsigned short* w2m = W2t + ((size_t)s * 16 + n) * 128 + q * 8;
#pragma unroll
        for (int ks = 0; ks < 4; ++ks) w2r[ks] = *(const short8*)(w2m + ks * 32);
    }

    // ---------- write x tile to LDS (swizzled rows) ----------
#pragma unroll
    for (int t = 0; t < 8; ++t) {
        const int i = tid + t * 256;
        const int r = i >> 7, c4 = i & 127;
        *(uint2*)((char*)xs + r * 1024 + ((c4 * 8) ^ ((r & 7) << 4))) = xp[t];
    }
    __syncthreads();

    // ---------- phase A: one MFMA per leaf module ----------
    {
        const int m0 = wv * 16;
        const unsigned short* w0fp = W0f + ((size_t)(s * 64 + m0) * 64 + lane) * 8;
        const float* bp = bias0g + (size_t)(s * 64 + m0) * 16 + q * 4;
        const int brow = lane & 15;
        const char* xrd = (const char*)xs + brow * 1024;
        char* h0wr = (char*)h0s + brow * 2048;
        FragG fA, fB;
        load4(fA, w0fp, bp, 0);
        load4(fB, w0fp, bp, 1);
        comp4(fA, 0, m0, xrd, h0wr, brow, q);
        load4(fA, w0fp, bp, 2);
        comp4(fB, 1, m0, xrd, h0wr, brow, q);
        load4(fB, w0fp, bp, 3);
        comp4(fA, 2, m0, xrd, h0wr, brow, q);
        comp4(fB, 3, m0, xrd, h0wr, brow, q);
    }
    __syncthreads();

    // ---------- phase B: h1 MFMA. wave wv -> modules {2wv, 2wv+1} ----------
    {
        char* const h0b = (char*)h0s;
        const int swn = (n & 7) << 4;          // read-side swizzle for row n
#pragma unroll
        for (int jj = 0; jj < 2; ++jj) {
            const int j = wv * 2 + jj;
            floatx4 acc = {0.f, 0.f, 0.f, 0.f};
#pragma unroll
            for (int ks = 0; ks < 4; ++ks) {
                const short8 av = *(const short8*)(h0b + n * 2048 +
                                   ((j * 256 + q * 16 + ks * 64) ^ swn));
                acc = __builtin_amdgcn_mfma_f32_16x16x32_bf16(av, w1r[jj][ks], acc, 0, 0, 0);
            }
#pragma unroll
            for (int r = 0; r < 4; ++r)
                h1u[(q * 4 + r) * H1S + j * 16 + n] = f2bf(sigf(acc[r]));
        }
    }
    __syncthreads();

    // ---------- phase C: h2 MFMA (module s), wave 0; agent-coherent stores ----
    if (wv == 0) {
        const unsigned short* am = &h1u[n * H1S + q * 8];
        floatx4 acc = {0.f, 0.f, 0.f, 0.f};
#pragma unroll
        for (int ks = 0; ks < 4; ++ks) {
            const short8 av = *(const short8*)(am + ks * 32);
            acc = __builtin_amdgcn_mfma_f32_16x16x32_bf16(av, w2r[ks], acc, 0, 0, 0);
        }
#pragma unroll
        for (int r = 0; r < 4; ++r)
            __hip_atomic_store(&h2ws[(size_t)(b0 + q * 4 + r) * 128 + s * 16 + n],
                               sigf(acc[r]), __ATOMIC_RELAXED,
                               __HIP_MEMORY_SCOPE_AGENT);
    }
    // __syncthreads drains vmcnt before s_barrier -> h2 stores are at the
    // coherent point (MALL) before any thread proceeds. No wbl2 anywhere.
    __syncthreads();
    if (tid == 0) {
        asm volatile("" ::: "memory");
        lastflag = (__hip_atomic_fetch_add(&cnt[tile], 1, __ATOMIC_RELAXED,
                                           __HIP_MEMORY_SCOPE_AGENT) == 7);
        asm volatile("" ::: "memory");
    }
    __syncthreads();

    // ---------- fused root: last slice-block of this tile ----------
    if (lastflag) {
        float* w3s = (float*)xs;               // 8 KB (xs/h1u dead)
        float* wfs = (float*)xs + 2048;
        *(float4*)&w3s[tid * 8]     = *(const float4*)(W3 + tid * 8);
        *(float4*)&w3s[tid * 8 + 4] = *(const float4*)(W3 + tid * 8 + 4);
        if (tid < 16) wfs[tid] = Wf[tid];
        __syncthreads();
        const int h = tid & 15;
        const int b = b0 + (tid >> 4);
        const float* hp = h2ws + (size_t)b * 128;
        float acc = 0.f;
#pragma unroll 8
        for (int k = 0; k < 128; ++k) {
            const float hv = __hip_atomic_load(&hp[k], __ATOMIC_RELAXED,
                                               __HIP_MEMORY_SCOPE_AGENT);
            acc = fmaf(hv, w3s[k * 16 + h], acc);
        }
        float v = sigf(acc) * wfs[h];
        v += __shfl_down(v, 8, 16);
        v += __shfl_down(v, 4, 16);
        v += __shfl_down(v, 2, 16);
        v += __shfl_down(v, 1, 16);
        if (h == 0) out[b] = v;
    }
}

extern "C" void kernel_launch(void* const* d_in, const int* in_sizes, int n_in,
                              void* d_out, int out_size, void* d_ws, size_t ws_size,
                              hipStream_t stream) {
    const float* x  = (const float*)d_in[0];
    const float* Wg = (const float*)d_in[1];
    const float* bg = (const float*)d_in[2];
    const float* W0 = (const float*)d_in[3];
    const float* W1 = (const float*)d_in[4];
    const float* W2 = (const float*)d_in[5];
    const float* W3 = (const float*)d_in[6];
    const float* Wf = (const float*)d_in[7];
    float* out = (float*)d_out;

    float* h2 = (float*)d_ws;                                          // 2 MB
    unsigned short* W1t = (unsigned short*)((char*)d_ws + (size_t)2 * 1024 * 1024); // 256 KB
    unsigned short* W2t = W1t + (size_t)64 * 2048;                                  //  32 KB
    unsigned short* W0f = (unsigned short*)((char*)d_ws + (size_t)2 * 1024 * 1024
                                                        + (size_t)512 * 1024);      // 512 KB
    float* bias0g = (float*)((char*)d_ws + (size_t)3 * 1024 * 1024);                //  32 KB
    int* cnt = (int*)((char*)d_ws + (size_t)3 * 1024 * 1024 + (size_t)64 * 1024);   //   1 KB

    k_prep<<<dim3(136), dim3(256), 0, stream>>>(W1, W2, Wg, bg, W0,
                                                W1t, W2t, W0f, bias0g, cnt);
    k_tree<<<dim3((4096 / TB) * 8), dim3(256), 0, stream>>>(
        x, W0f, bias0g, W1t, W2t, W3, Wf, h2, cnt, out);
}

// Round 8
// 119.885 us; speedup vs baseline: 1.0788x; 1.0788x over previous
//
#include <hip/hip_runtime.h>
#include <hip/hip_bf16.h>

// RestrictedNN DAG. Round 12: delete k_root via LINEAR partial-root atomics.
//  - R7 (__threadfence -> wbl2 flood) and R11 (agent-scope sc-atomics ->
//    MALL-latency h2 path) both failed. This version never materializes h2
//    globally: root pre-activation p = h2·W3 is linear in h2, so each
//    s-block computes its 16-wide partial dot in-LDS (wave 0) and
//    plain-atomicAdd's (device scope, no fences, L2-resident) into p[B,16].
//  - k_final (16 blocks): out[b] = sum_h sigmoid(p[b,h])*Wf[h]. Reads 256 KB
//    (vs k_root's 2 MB h2 re-read through a poison-evicted MALL).
//  - k_tree phases A/B and all layouts identical to round 10b (best: 117.6).
//  - f32 summation order is the only numeric change vs round 10b -> absmax
//    unchanged.
// B=4096, L0=512 leaves (G=8,H=16), L1=64, L2=8 (FAN=8), root 128->16.

#define TB 16
#define H1S 136      // ushorts per h1 row (128+8): rows 16B-aligned

typedef __attribute__((ext_vector_type(8))) short short8;
typedef __attribute__((ext_vector_type(4))) float floatx4;

__device__ __forceinline__ float sigf(float v) {
    return __builtin_amdgcn_rcpf(1.0f + __expf(-v));
}
// packed f32x2 -> bf16x2 (RNE). Compiler emits v_cvt_pk_bf16_f32.
__device__ __forceinline__ unsigned int f2bf2(float lo, float hi) {
    __hip_bfloat162 p = __float22bfloat162_rn(make_float2(lo, hi));
    unsigned int u;
    __builtin_memcpy(&u, &p, 4);
    return u;
}
__device__ __forceinline__ unsigned short f2bf(float f) {
    __hip_bfloat16 b = __float2bfloat16(f);
    unsigned short u;
    __builtin_memcpy(&u, &b, 2);
    return u;
}

// ---- prep ----
// blocks 0..71 : transpose W1/W2 per module to bf16 [h][k] fragment layout
// blocks 72..135: build W0f (per-module 64-lane A-frag table, bf16 Wg*W0,
//                zero K-pad) and bias0 (f32, = bg . W0)
// all blocks: zero the root partial-sum buffer p[4096][16].
__global__ __launch_bounds__(256) void k_prep(
    const float* __restrict__ W1, const float* __restrict__ W2,
    const float* __restrict__ Wg, const float* __restrict__ bg,
    const float* __restrict__ W0,
    unsigned short* __restrict__ W1t, unsigned short* __restrict__ W2t,
    unsigned short* __restrict__ W0f, float* __restrict__ bias0g,
    float* __restrict__ pbuf)
{
    __shared__ float wl[128 * 17];
    const int mb  = blockIdx.x;
    const int tid = threadIdx.x;
    // zero pbuf: 4096*16 f32 = 16384 float4s over 136*256 threads
    {
        const int u = mb * 256 + tid;
        if (u < 16384)
            *(float4*)(pbuf + (size_t)u * 4) = make_float4(0.f, 0.f, 0.f, 0.f);
    }
    if (mb < 72) {
        const float* src = (mb < 64) ? (W1 + (size_t)mb * 2048)
                                     : (W2 + (size_t)(mb - 64) * 2048);
        unsigned short* dst = (mb < 64) ? (W1t + (size_t)mb * 2048)
                                        : (W2t + (size_t)(mb - 64) * 2048);
#pragma unroll
        for (int i = 0; i < 8; ++i) {
            const int idx = tid + i * 256;      // [k][h] in, coalesced
            wl[(idx >> 4) * 17 + (idx & 15)] = src[idx];
        }
        __syncthreads();
#pragma unroll
        for (int i = 0; i < 4; ++i) {
            const int u  = tid + i * 256;       // uint index over [h][k] bf16 out
            const int h  = u >> 6;
            const int k  = (u & 63) * 2;
            ((unsigned int*)dst)[u] = f2bf2(wl[k * 17 + h], wl[(k + 1) * 17 + h]);
        }
    } else {
        const int idx = mb - 72;                // 0..63, 8 modules each
        const int sub = tid >> 6, l = tid & 63;
#pragma unroll
        for (int it = 0; it < 2; ++it) {
            const int m = idx * 8 + it * 4 + sub;
            uint4 v = make_uint4(0u, 0u, 0u, 0u);
            if (l < 16) {
                float p[8];
                float bsum = 0.f;
#pragma unroll
                for (int j = 0; j < 8; ++j) {
                    const float w = W0[(size_t)m * 128 + j * 16 + l];
                    p[j] = Wg[m * 8 + j] * w;
                    bsum = fmaf(bg[m * 8 + j], w, bsum);
                }
                v.x = f2bf2(p[0], p[1]);
                v.y = f2bf2(p[2], p[3]);
                v.z = f2bf2(p[4], p[5]);
                v.w = f2bf2(p[6], p[7]);
                bias0g[m * 16 + l] = bsum;
            }
            *(uint4*)(W0f + (size_t)m * 512 + l * 8) = v;
        }
    }
}

// 2x4-deep software-pipeline regs for phase A (static indices only)
struct FragG { uint4 a0, a1, a2, a3; float4 b0, b1, b2, b3; };

__device__ __forceinline__ void load4(FragG& f, const unsigned short* w0fp,
                                      const float* bp, int g) {
    f.a0 = *(const uint4*)(w0fp + (size_t)(g * 4 + 0) * 512);
    f.a1 = *(const uint4*)(w0fp + (size_t)(g * 4 + 1) * 512);
    f.a2 = *(const uint4*)(w0fp + (size_t)(g * 4 + 2) * 512);
    f.a3 = *(const uint4*)(w0fp + (size_t)(g * 4 + 3) * 512);
    f.b0 = *(const float4*)(bp + (g * 4 + 0) * 16);
    f.b1 = *(const float4*)(bp + (g * 4 + 1) * 16);
    f.b2 = *(const float4*)(bp + (g * 4 + 2) * 16);
    f.b3 = *(const float4*)(bp + (g * 4 + 3) * 16);
}

__device__ __forceinline__ void comp4(const FragG& f, int g, int m0,
                                      const char* xrd, char* h0wr,
                                      int brow, int q) {
#pragma unroll
    for (int i = 0; i < 4; ++i) {
        const uint4  a4 = (i == 0) ? f.a0 : (i == 1) ? f.a1 : (i == 2) ? f.a2 : f.a3;
        const float4 b4 = (i == 0) ? f.b0 : (i == 1) ? f.b1 : (i == 2) ? f.b2 : f.b3;
        const int mloc = m0 + g * 4 + i;
        const short8 bv = *(const short8*)(xrd + ((mloc * 16) ^ ((brow & 7) << 4)));
        floatx4 acc = {b4.x, b4.y, b4.z, b4.w};
        acc = __builtin_amdgcn_mfma_f32_16x16x32_bf16(
                  __builtin_bit_cast(short8, a4), bv, acc, 0, 0, 0);
        *(uint2*)(h0wr + ((mloc * 32 + q * 8) ^ ((brow & 7) << 4))) =
            make_uint2(f2bf2(sigf(acc[0]), sigf(acc[1])),
                       f2bf2(sigf(acc[2]), sigf(acc[3])));
    }
}

__global__ __launch_bounds__(256, 3) void k_tree(
    const float* __restrict__ x,
    const unsigned short* __restrict__ W0f, const float* __restrict__ bias0g,
    const unsigned short* __restrict__ W1t, const unsigned short* __restrict__ W2t,
    const float* __restrict__ W3, float* __restrict__ pbuf)
{
    __shared__ __align__(16) unsigned short xs[16 * 512];     // 16384 B (h1 reuses)
    __shared__ __align__(16) unsigned short h0s[16 * 1024];   // 32768 B, swizzled
    unsigned short* h1u = xs;   // h1 [b][j*16+h] bf16, stride H1S; xs dead after A

    const int tid  = threadIdx.x;
    const int s    = blockIdx.x & 7;
    const int b0   = (blockIdx.x >> 3) * TB;
    const int lane = tid & 63;
    const int wv   = tid >> 6;
    const int n    = lane & 15, q = lane >> 4;

    // ---------- issue x stage loads (oldest in pipe), convert as they land ----
    const float* xbase = x + (size_t)b0 * 4096 + s * 512;
    uint2 xp[8];
#pragma unroll
    for (int t = 0; t < 8; ++t) {
        const int i = tid + t * 256;           // over TB*128 float4s
        const int r = i >> 7, c4 = i & 127;
        const float4 v = *(const float4*)(xbase + (size_t)r * 4096 + c4 * 4);
        xp[t] = make_uint2(f2bf2(v.x, v.y), f2bf2(v.z, v.w));
    }

    // ---------- prefetch phase-B/C MFMA B-fragments ----------
    short8 w1r[2][4];
#pragma unroll
    for (int jj = 0; jj < 2; ++jj) {
        const unsigned short* w1m =
            W1t + ((size_t)(s * 8 + wv * 2 + jj) * 16 + n) * 128 + q * 8;
#pragma unroll
        for (int ks = 0; ks < 4; ++ks)
            w1r[jj][ks] = *(const short8*)(w1m + ks * 32);
    }
    short8 w2r[4];
    if (wv == 0) {
        const unsigned short* w2m = W2t + ((size_t)s * 16 + n) * 128 + q * 8;
#pragma unroll
        for (int ks = 0; ks < 4; ++ks) w2r[ks] = *(const short8*)(w2m + ks * 32);
    }

    // ---------- write x tile to LDS (swizzled rows) ----------
#pragma unroll
    for (int t = 0; t < 8; ++t) {
        const int i = tid + t * 256;
        const int r = i >> 7, c4 = i & 127;
        *(uint2*)((char*)xs + r * 1024 + ((c4 * 8) ^ ((r & 7) << 4))) = xp[t];
    }
    __syncthreads();

    // ---------- phase A: one MFMA per leaf module ----------
    {
        const int m0 = wv * 16;
        const unsigned short* w0fp = W0f + ((size_t)(s * 64 + m0) * 64 + lane) * 8;
        const float* bp = bias0g + (size_t)(s * 64 + m0) * 16 + q * 4;
        const int brow = lane & 15;
        const char* xrd = (const char*)xs + brow * 1024;
        char* h0wr = (char*)h0s + brow * 2048;
        FragG fA, fB;
        load4(fA, w0fp, bp, 0);
        load4(fB, w0fp, bp, 1);
        comp4(fA, 0, m0, xrd, h0wr, brow, q);
        load4(fA, w0fp, bp, 2);
        comp4(fB, 1, m0, xrd, h0wr, brow, q);
        load4(fB, w0fp, bp, 3);
        comp4(fA, 2, m0, xrd, h0wr, brow, q);
        comp4(fB, 3, m0, xrd, h0wr, brow, q);
    }
    __syncthreads();

    // ---------- phase B: h1 MFMA. wave wv -> modules {2wv, 2wv+1} ----------
    {
        char* const h0b = (char*)h0s;
        const int swn = (n & 7) << 4;          // read-side swizzle for row n
#pragma unroll
        for (int jj = 0; jj < 2; ++jj) {
            const int j = wv * 2 + jj;
            floatx4 acc = {0.f, 0.f, 0.f, 0.f};
#pragma unroll
            for (int ks = 0; ks < 4; ++ks) {
                const short8 av = *(const short8*)(h0b + n * 2048 +
                                   ((j * 256 + q * 16 + ks * 64) ^ swn));
                acc = __builtin_amdgcn_mfma_f32_16x16x32_bf16(av, w1r[jj][ks], acc, 0, 0, 0);
            }
#pragma unroll
            for (int r = 0; r < 4; ++r)
                h1u[(q * 4 + r) * H1S + j * 16 + n] = f2bf(sigf(acc[r]));
        }
    }
    __syncthreads();

    // ---------- phase C: h2 MFMA (module s) + partial root dot, wave 0 ----
    if (wv == 0) {
        // stage W3 slice [n=0..15][h=0..15] into dead xs space (1 KB)
        float* h2l = (float*)((char*)xs + 8192);    // [b_local][n] 16x16 f32
        float* w3l = (float*)((char*)xs + 12288);   // [n][h]      16x16 f32
        {
            const int nn = lane >> 2, h4 = (lane & 3) * 4;
            *(float4*)&w3l[nn * 16 + h4] =
                *(const float4*)(W3 + (size_t)(s * 16 + nn) * 16 + h4);
        }
        const unsigned short* am = &h1u[n * H1S + q * 8];
        floatx4 acc = {0.f, 0.f, 0.f, 0.f};
#pragma unroll
        for (int ks = 0; ks < 4; ++ks) {
            const short8 av = *(const short8*)(am + ks * 32);
            acc = __builtin_amdgcn_mfma_f32_16x16x32_bf16(av, w2r[ks], acc, 0, 0, 0);
        }
#pragma unroll
        for (int r = 0; r < 4; ++r)
            h2l[(q * 4 + r) * 16 + n] = sigf(acc[r]);
        __builtin_amdgcn_wave_barrier();       // keep LDS write->read order
        // lane l: batch b = l&15, h = (l>>4) + 4j.  DS pipe is in-order per
        // wave, so the cross-lane h2l/w3l reads below see the writes above.
        const int b = lane & 15;
        float pacc[4] = {0.f, 0.f, 0.f, 0.f};
#pragma unroll
        for (int k = 0; k < 16; ++k) {
            const float hv = h2l[b * 16 + k];
#pragma unroll
            for (int j = 0; j < 4; ++j)
                pacc[j] = fmaf(hv, w3l[k * 16 + (q + 4 * j)], pacc[j]);
        }
#pragma unroll
        for (int j = 0; j < 4; ++j)
            atomicAdd(&pbuf[(size_t)(b0 + b) * 16 + q + 4 * j], pacc[j]);
    }
}

// ---------- kernel: out[b] = sum_h sigmoid(p[b,h]) * Wf[h] ----------
__global__ __launch_bounds__(256) void k_final(
    const float* __restrict__ pbuf, const float* __restrict__ Wf,
    float* __restrict__ out)
{
    __shared__ float wfs[16];
    const int tid = threadIdx.x;
    if (tid < 16) wfs[tid] = Wf[tid];
    __syncthreads();
    const int b = blockIdx.x * 256 + tid;
    const float4* pp = (const float4*)(pbuf + (size_t)b * 16);
    const float4 p0 = pp[0], p1 = pp[1], p2 = pp[2], p3 = pp[3];
    float v = 0.f;
    v = fmaf(sigf(p0.x), wfs[0],  v);
    v = fmaf(sigf(p0.y), wfs[1],  v);
    v = fmaf(sigf(p0.z), wfs[2],  v);
    v = fmaf(sigf(p0.w), wfs[3],  v);
    v = fmaf(sigf(p1.x), wfs[4],  v);
    v = fmaf(sigf(p1.y), wfs[5],  v);
    v = fmaf(sigf(p1.z), wfs[6],  v);
    v = fmaf(sigf(p1.w), wfs[7],  v);
    v = fmaf(sigf(p2.x), wfs[8],  v);
    v = fmaf(sigf(p2.y), wfs[9],  v);
    v = fmaf(sigf(p2.z), wfs[10], v);
    v = fmaf(sigf(p2.w), wfs[11], v);
    v = fmaf(sigf(p3.x), wfs[12], v);
    v = fmaf(sigf(p3.y), wfs[13], v);
    v = fmaf(sigf(p3.z), wfs[14], v);
    v = fmaf(sigf(p3.w), wfs[15], v);
    out[b] = v;
}

extern "C" void kernel_launch(void* const* d_in, const int* in_sizes, int n_in,
                              void* d_out, int out_size, void* d_ws, size_t ws_size,
                              hipStream_t stream) {
    const float* x  = (const float*)d_in[0];
    const float* Wg = (const float*)d_in[1];
    const float* bg = (const float*)d_in[2];
    const float* W0 = (const float*)d_in[3];
    const float* W1 = (const float*)d_in[4];
    const float* W2 = (const float*)d_in[5];
    const float* W3 = (const float*)d_in[6];
    const float* Wf = (const float*)d_in[7];
    float* out = (float*)d_out;

    float* pbuf = (float*)d_ws;                                        // 256 KB
    unsigned short* W1t = (unsigned short*)((char*)d_ws + (size_t)2 * 1024 * 1024); // 256 KB
    unsigned short* W2t = W1t + (size_t)64 * 2048;                                  //  32 KB
    unsigned short* W0f = (unsigned short*)((char*)d_ws + (size_t)2 * 1024 * 1024
                                                        + (size_t)512 * 1024);      // 512 KB
    float* bias0g = (float*)((char*)d_ws + (size_t)3 * 1024 * 1024);                //  32 KB

    k_prep<<<dim3(136), dim3(256), 0, stream>>>(W1, W2, Wg, bg, W0,
                                                W1t, W2t, W0f, bias0g, pbuf);
    k_tree<<<dim3((4096 / TB) * 8), dim3(256), 0, stream>>>(
        x, W0f, bias0g, W1t, W2t, W3, pbuf);
    k_final<<<dim3(4096 / 256), dim3(256), 0, stream>>>(pbuf, Wf, out);
}